// Round 2
// baseline (306.043 us; speedup 1.0000x reference)
//
#include <hip/hip_runtime.h>
#include <hip/hip_bf16.h>
#include <stdint.h>

// Problem constants: N=8, T=200, U=50, E=D=J=512, V=500. M = N*T*U = 80000.
#define JD 512
#define VV 500

typedef short short8 __attribute__((ext_vector_type(8)));
typedef short short4v __attribute__((ext_vector_type(4)));
typedef float floatx4 __attribute__((ext_vector_type(4)));

__device__ inline short f2bf(float f) {
    uint32_t u = __float_as_uint(f);
    uint32_t r = (u + 0x7FFFu + ((u >> 16) & 1u)) >> 16;
    return (short)r;
}

__device__ inline float fast_tanh(float x) {
    // tanh(x) = 1 - 2/(exp(2x)+1); v_exp_f32 is exp2 natively.
    float e = __builtin_amdgcn_exp2f(x * 2.8853900817779268f); // 2*log2(e)
    return 1.0f - 2.0f * __builtin_amdgcn_rcpf(e + 1.0f);
}

// ---------------------------------------------------------------------------
// Kernel 1: pad+cast W_out -> Wb (512x512 bf16, zero rows 500..511).
// enc/dec/Wenc/Wdec conversions happen inline in proj_gemm staging.
// ---------------------------------------------------------------------------
__global__ __launch_bounds__(256) void prep_kernel(
    const float* __restrict__ Wout, short* __restrict__ Wb)
{
    int i = blockIdx.x * 256 + threadIdx.x;   // grid covers 262144 exactly
    int row = i >> 9, col = i & 511;
    Wb[i] = (row < VV) ? f2bf(Wout[row * JD + col]) : (short)0;
}

// ---------------------------------------------------------------------------
// Kernel 2: projection GEMMs (enc: 1600x512x512, dec: 400x512x512).
// Reads fp32 activations/weights directly, converts to bf16 while staging to
// LDS (removes the separate cast pass). BM=64 x BN=128 tiles -> 128 blocks
// (2x the CU coverage of the old 68-block version). LDS row stride 72 shorts
// (+4 banks/row) keeps b128 frag reads at the conflict minimum.
// ---------------------------------------------------------------------------
#define PST 72
__global__ __launch_bounds__(256) void proj_gemm(
    const float* __restrict__ enc, const float* __restrict__ dec,
    const float* __restrict__ Wenc, const float* __restrict__ Wdec,
    const float* __restrict__ b_enc, const float* __restrict__ b_dec,
    float* __restrict__ enc_p, float* __restrict__ dec_p)
{
    __shared__ short As[64 * PST];    //  9,216 B
    __shared__ short Bs[128 * PST];   // 18,432 B
    int bx = blockIdx.x, by = blockIdx.y;
    const float* A; const float* W; const float* bias; float* C; int M;
    if (bx < 25) { A = enc; W = Wenc; bias = b_enc; C = enc_p; M = 1600; }
    else { bx -= 25; A = dec; W = Wdec; bias = b_dec; C = dec_p; M = 400; }

    int tid = threadIdx.x;
    int lane = tid & 63, wv = tid >> 6;
    int wm = wv >> 1, wn = wv & 1;          // 2x2 wave grid, wave tile 32x64
    int l16 = lane & 15, q4 = lane >> 4;

    int ra = tid >> 2, ha = tid & 3;        // A stage: row 0..63, 16-float k-chunk
    int rb = tid >> 1, hb = tid & 1;        // B stage: row 0..127, 32-float k-chunk
    int m_st = bx * 64 + ra;
    bool valid = m_st < M;

    floatx4 acc[2][4];
    #pragma unroll
    for (int a = 0; a < 2; a++)
        #pragma unroll
        for (int b = 0; b < 4; b++) acc[a][b] = (floatx4){0.f, 0.f, 0.f, 0.f};

    for (int kk = 0; kk < 8; kk++) {
        int k0 = kk * 64;
        __syncthreads();
        {
            // ---- A tile: 64 rows x 64 k, fp32 -> bf16
            float4 v0 = make_float4(0.f, 0.f, 0.f, 0.f);
            float4 v1 = v0, v2 = v0, v3 = v0;
            if (valid) {
                const float4* p = (const float4*)(A + (size_t)m_st * JD + k0 + ha * 16);
                v0 = p[0]; v1 = p[1]; v2 = p[2]; v3 = p[3];
            }
            short8 o0, o1;
            o0[0] = f2bf(v0.x); o0[1] = f2bf(v0.y); o0[2] = f2bf(v0.z); o0[3] = f2bf(v0.w);
            o0[4] = f2bf(v1.x); o0[5] = f2bf(v1.y); o0[6] = f2bf(v1.z); o0[7] = f2bf(v1.w);
            o1[0] = f2bf(v2.x); o1[1] = f2bf(v2.y); o1[2] = f2bf(v2.z); o1[3] = f2bf(v2.w);
            o1[4] = f2bf(v3.x); o1[5] = f2bf(v3.y); o1[6] = f2bf(v3.z); o1[7] = f2bf(v3.w);
            *(short8*)&As[ra * PST + ha * 16]     = o0;
            *(short8*)&As[ra * PST + ha * 16 + 8] = o1;

            // ---- B tile: 128 rows x 64 k, fp32 -> bf16
            const float4* pb = (const float4*)(W + (size_t)(by * 128 + rb) * JD + k0 + hb * 32);
            float4 w0 = pb[0], w1 = pb[1], w2 = pb[2], w3 = pb[3];
            float4 w4 = pb[4], w5 = pb[5], w6 = pb[6], w7 = pb[7];
            short8 p0, p1, p2, p3;
            p0[0] = f2bf(w0.x); p0[1] = f2bf(w0.y); p0[2] = f2bf(w0.z); p0[3] = f2bf(w0.w);
            p0[4] = f2bf(w1.x); p0[5] = f2bf(w1.y); p0[6] = f2bf(w1.z); p0[7] = f2bf(w1.w);
            p1[0] = f2bf(w2.x); p1[1] = f2bf(w2.y); p1[2] = f2bf(w2.z); p1[3] = f2bf(w2.w);
            p1[4] = f2bf(w3.x); p1[5] = f2bf(w3.y); p1[6] = f2bf(w3.z); p1[7] = f2bf(w3.w);
            p2[0] = f2bf(w4.x); p2[1] = f2bf(w4.y); p2[2] = f2bf(w4.z); p2[3] = f2bf(w4.w);
            p2[4] = f2bf(w5.x); p2[5] = f2bf(w5.y); p2[6] = f2bf(w5.z); p2[7] = f2bf(w5.w);
            p3[0] = f2bf(w6.x); p3[1] = f2bf(w6.y); p3[2] = f2bf(w6.z); p3[3] = f2bf(w6.w);
            p3[4] = f2bf(w7.x); p3[5] = f2bf(w7.y); p3[6] = f2bf(w7.z); p3[7] = f2bf(w7.w);
            short* bdst = &Bs[rb * PST + hb * 32];
            *(short8*)(bdst)      = p0;
            *(short8*)(bdst + 8)  = p1;
            *(short8*)(bdst + 16) = p2;
            *(short8*)(bdst + 24) = p3;
        }
        __syncthreads();
        #pragma unroll
        for (int h2 = 0; h2 < 2; h2++) {
            short8 af[2], bf[4];
            #pragma unroll
            for (int im = 0; im < 2; im++)
                af[im] = *(const short8*)&As[(wm * 32 + im * 16 + l16) * PST + h2 * 32 + q4 * 8];
            #pragma unroll
            for (int in = 0; in < 4; in++)
                bf[in] = *(const short8*)&Bs[(wn * 64 + in * 16 + l16) * PST + h2 * 32 + q4 * 8];
            #pragma unroll
            for (int im = 0; im < 2; im++)
                #pragma unroll
                for (int in = 0; in < 4; in++)
                    acc[im][in] = __builtin_amdgcn_mfma_f32_16x16x32_bf16(
                        af[im], bf[in], acc[im][in], 0, 0, 0);
        }
    }
    #pragma unroll
    for (int im = 0; im < 2; im++) {
        int mb = bx * 64 + wm * 32 + im * 16 + q4 * 4;
        #pragma unroll
        for (int rr = 0; rr < 4; rr++) {
            int m = mb + rr;
            if (m < M) {
                #pragma unroll
                for (int in = 0; in < 4; in++) {
                    int j = by * 128 + wn * 64 + in * 16 + l16;
                    C[(size_t)m * JD + j] = acc[im][in][rr] + bias[j];
                }
            }
        }
    }
}

// ---------------------------------------------------------------------------
// Kernel 3: FUSED act + vocab GEMM.
// v2: M-tile halved 128 -> 64 rows so LDS = 64*520*2 = 66,560 B -> TWO
// independent blocks co-resident per CU (was 1 at 133 KB). The three phases
// (tanh VALU burst -> MFMA k-loop -> 256KB store burst) previously serialized
// with nothing to hide them; now one block's stores/tanh overlap the other's
// MFMAs. 256 threads = 4 waves (1x4), wave tile 64x128, acc 4x8 floatx4;
// 2 blocks x 4 waves = 8 waves/CU at <=256 VGPR (launch_bounds(256,2)).
// Grid 1250 (tail granularity 2x finer). Row stride 520 shorts keeps frag
// reads at the b128 conflict minimum.
// ---------------------------------------------------------------------------
#define AST 520
__global__ __launch_bounds__(256, 2) void fused_joiner(
    const float* __restrict__ enc_p, const float* __restrict__ dec_p,
    const short* __restrict__ Wb, const float* __restrict__ b_out,
    float* __restrict__ out)
{
    __shared__ short As[64 * AST];   // 66,560 B -> 2 blocks/CU
    int tid = threadIdx.x;
    int bx = blockIdx.x;

    // ---- Phase 1: act tile (64 m-rows x 512 j) -> LDS
    {
        int rsub = tid >> 7;            // 0..1 rows per pass
        int jf = (tid & 127) * 4;       // fp32 j offset, coalesced per row
        #pragma unroll 4
        for (int pass = 0; pass < 32; pass++) {
            int row = pass * 2 + rsub;
            int m = bx * 64 + row;
            int er = m / 50;            // n*200 + t
            int n  = m / 10000;
            int dr = n * 50 + (m - er * 50);
            float4 e = *(const float4*)(enc_p + (size_t)er * JD + jf);
            float4 d = *(const float4*)(dec_p + (size_t)dr * JD + jf);
            short4v o;
            o[0] = f2bf(fast_tanh(e.x + d.x));
            o[1] = f2bf(fast_tanh(e.y + d.y));
            o[2] = f2bf(fast_tanh(e.z + d.z));
            o[3] = f2bf(fast_tanh(e.w + d.w));
            *(short4v*)&As[row * AST + jf] = o;
        }
    }
    __syncthreads();

    // ---- Phase 2: GEMM out[64 x 512] = act x Wb^T over K=512
    int lane = tid & 63, wn = tid >> 6;   // 4 waves, 1x4 grid
    int l16 = lane & 15, q4 = lane >> 4;

    floatx4 acc[4][8];
    #pragma unroll
    for (int a = 0; a < 4; a++)
        #pragma unroll
        for (int b = 0; b < 8; b++) acc[a][b] = (floatx4){0.f, 0.f, 0.f, 0.f};

    int abase[4];
    #pragma unroll
    for (int im = 0; im < 4; im++)
        abase[im] = (im * 16 + l16) * AST + q4 * 8;
    int boff[8];
    #pragma unroll
    for (int in = 0; in < 8; in++)
        boff[in] = (wn * 128 + in * 16 + l16) * JD + q4 * 8;

    // B double-buffer from L2-resident Wb (512 KB)
    short8 b0[8], b1[8];
    #pragma unroll
    for (int in = 0; in < 8; in++)
        b0[in] = *(const short8*)(Wb + boff[in]);

    for (int ks = 0; ks < 16; ks += 2) {
        int k1 = (ks + 1) * 32;
        #pragma unroll
        for (int in = 0; in < 8; in++)
            b1[in] = *(const short8*)(Wb + boff[in] + k1);
        {
            int k0 = ks * 32;
            short8 af[4];
            #pragma unroll
            for (int im = 0; im < 4; im++)
                af[im] = *(const short8*)&As[abase[im] + k0];
            #pragma unroll
            for (int im = 0; im < 4; im++)
                #pragma unroll
                for (int in = 0; in < 8; in++)
                    acc[im][in] = __builtin_amdgcn_mfma_f32_16x16x32_bf16(
                        af[im], b0[in], acc[im][in], 0, 0, 0);
        }
        if (ks + 2 < 16) {
            int k2 = (ks + 2) * 32;
            #pragma unroll
            for (int in = 0; in < 8; in++)
                b0[in] = *(const short8*)(Wb + boff[in] + k2);
        }
        {
            short8 af[4];
            #pragma unroll
            for (int im = 0; im < 4; im++)
                af[im] = *(const short8*)&As[abase[im] + k1];
            #pragma unroll
            for (int im = 0; im < 4; im++)
                #pragma unroll
                for (int in = 0; in < 8; in++)
                    acc[im][in] = __builtin_amdgcn_mfma_f32_16x16x32_bf16(
                        af[im], b1[in], acc[im][in], 0, 0, 0);
        }
    }

    // ---- Epilogue: bias + store (m always < 80000; guard v < 500)
    float bo[8];
    #pragma unroll
    for (int in = 0; in < 8; in++) {
        int v = wn * 128 + in * 16 + l16;
        bo[in] = (v < VV) ? b_out[v] : 0.f;
    }
    #pragma unroll
    for (int im = 0; im < 4; im++) {
        int mb = bx * 64 + im * 16 + q4 * 4;
        #pragma unroll
        for (int rr = 0; rr < 4; rr++) {
            size_t orow = (size_t)(mb + rr) * VV;
            #pragma unroll
            for (int in = 0; in < 8; in++) {
                int v = wn * 128 + in * 16 + l16;
                if (v < VV) out[orow + v] = acc[im][in][rr] + bo[in];
            }
        }
    }
}

// ---------------------------------------------------------------------------
extern "C" void kernel_launch(void* const* d_in, const int* in_sizes, int n_in,
                              void* d_out, int out_size, void* d_ws, size_t ws_size,
                              hipStream_t stream)
{
    const float* enc   = (const float*)d_in[0];
    const float* dec   = (const float*)d_in[1];
    const float* Wenc  = (const float*)d_in[2];
    const float* b_enc = (const float*)d_in[3];
    const float* Wdec  = (const float*)d_in[4];
    const float* b_dec = (const float*)d_in[5];
    const float* Wout  = (const float*)d_in[6];
    const float* b_out = (const float*)d_in[7];
    float* out = (float*)d_out;

    // ws layout (bytes): ~4.6 MB total
    char* ws = (char*)d_ws;
    short* Wb    = (short*)(ws + 0);          // 512*512 bf16 = 524,288 B
    float* enc_p = (float*)(ws + 524288);     // 1600*512 f32 = 3,276,800 B
    float* dec_p = (float*)(ws + 3801088);    //  400*512 f32 =   819,200 B

    prep_kernel<<<1024, 256, 0, stream>>>(Wout, Wb);
    proj_gemm<<<dim3(32, 4), 256, 0, stream>>>(enc, dec, Wenc, Wdec,
                                               b_enc, b_dec, enc_p, dec_p);
    fused_joiner<<<1250, 256, 0, stream>>>(enc_p, dec_p, Wb, b_out, out);
}

// Round 3
// 250.531 us; speedup vs baseline: 1.2216x; 1.2216x over previous
//
#include <hip/hip_runtime.h>
#include <hip/hip_bf16.h>
#include <stdint.h>

// Problem constants: N=8, T=200, U=50, E=D=J=512, V=500. M = N*T*U = 80000.
#define JD 512
#define VV 500

typedef short short8 __attribute__((ext_vector_type(8)));
typedef short short4v __attribute__((ext_vector_type(4)));
typedef float floatx4 __attribute__((ext_vector_type(4)));

__device__ inline short f2bf(float f) {
    uint32_t u = __float_as_uint(f);
    uint32_t r = (u + 0x7FFFu + ((u >> 16) & 1u)) >> 16;
    return (short)r;
}

__device__ inline float fast_tanh(float x) {
    // tanh(x) = 1 - 2/(exp(2x)+1); v_exp_f32 is exp2 natively.
    float e = __builtin_amdgcn_exp2f(x * 2.8853900817779268f); // 2*log2(e)
    return 1.0f - 2.0f * __builtin_amdgcn_rcpf(e + 1.0f);
}

// ---------------------------------------------------------------------------
// Kernel 1: W_out -> WbF in FRAGMENT-NATIVE order (bf16, rows 500..511 = 0).
// WbF[vblk][ks][q4][l16][e] , short index:
//   vblk*8192 + ks*512 + q4*128 + l16*8 + e
// holds Wout[v = vblk*16+l16][k = ks*32 + q4*8 + e].
// With this layout a wave's B-fragment load (lanes = (l16,q4)) is ONE
// contiguous 1 KiB read (16 B/lane) instead of a 64-cache-line gather at
// stride 1024 B. The gather was saturating the per-CU L1/TA port and is the
// round-2 diagnosis for MfmaUtil stuck at 11% regardless of occupancy.
// ---------------------------------------------------------------------------
__global__ __launch_bounds__(256) void prep_kernel(
    const float* __restrict__ Wout, short* __restrict__ WbF)
{
    int j = blockIdx.x * 256 + threadIdx.x;   // 32768 threads, 8 shorts each
    int l16  = j & 15;
    int q4   = (j >> 4) & 3;
    int ks   = (j >> 6) & 15;
    int vblk = j >> 10;                        // 0..31
    int v  = vblk * 16 + l16;
    int k0 = ks * 32 + q4 * 8;
    short8 o;
    if (v < VV) {
        const float4* p = (const float4*)(Wout + (size_t)v * JD + k0);
        float4 a = p[0], b = p[1];
        o[0] = f2bf(a.x); o[1] = f2bf(a.y); o[2] = f2bf(a.z); o[3] = f2bf(a.w);
        o[4] = f2bf(b.x); o[5] = f2bf(b.y); o[6] = f2bf(b.z); o[7] = f2bf(b.w);
    } else {
        o = (short8){0,0,0,0,0,0,0,0};
    }
    *(short8*)(WbF + (size_t)j * 8) = o;       // coalesced 16 B/lane
}

// ---------------------------------------------------------------------------
// Kernel 2: projection GEMMs (enc: 1600x512x512, dec: 400x512x512).
// fp32 read + inline bf16 convert while staging to LDS. BM=64 x BN=64 tiles
// -> 256 blocks (1/CU; was 128 -> half the CUs idle). LDS stride 72 shorts.
// ---------------------------------------------------------------------------
#define PST 72
__global__ __launch_bounds__(256) void proj_gemm(
    const float* __restrict__ enc, const float* __restrict__ dec,
    const float* __restrict__ Wenc, const float* __restrict__ Wdec,
    const float* __restrict__ b_enc, const float* __restrict__ b_dec,
    float* __restrict__ enc_p, float* __restrict__ dec_p)
{
    __shared__ short As[64 * PST];    // 9,216 B
    __shared__ short Bs[64 * PST];    // 9,216 B
    int bx = blockIdx.x, by = blockIdx.y;
    const float* A; const float* W; const float* bias; float* C; int M;
    if (bx < 25) { A = enc; W = Wenc; bias = b_enc; C = enc_p; M = 1600; }
    else { bx -= 25; A = dec; W = Wdec; bias = b_dec; C = dec_p; M = 400; }

    int tid = threadIdx.x;
    int lane = tid & 63, wv = tid >> 6;
    int wm = wv >> 1, wn = wv & 1;          // 2x2 wave grid, wave tile 32x32
    int l16 = lane & 15, q4 = lane >> 4;

    int ra = tid >> 2, ha = tid & 3;        // stage: row 0..63, 16-float k-chunk
    int m_st = bx * 64 + ra;
    bool valid = m_st < M;
    int wrow = by * 64 + ra;                // always < 512

    floatx4 acc[2][2];
    #pragma unroll
    for (int a = 0; a < 2; a++)
        #pragma unroll
        for (int b = 0; b < 2; b++) acc[a][b] = (floatx4){0.f, 0.f, 0.f, 0.f};

    for (int kk = 0; kk < 8; kk++) {
        int k0 = kk * 64;
        __syncthreads();
        {
            // ---- A tile: 64 rows x 64 k, fp32 -> bf16
            float4 v0 = make_float4(0.f, 0.f, 0.f, 0.f);
            float4 v1 = v0, v2 = v0, v3 = v0;
            if (valid) {
                const float4* p = (const float4*)(A + (size_t)m_st * JD + k0 + ha * 16);
                v0 = p[0]; v1 = p[1]; v2 = p[2]; v3 = p[3];
            }
            short8 o0, o1;
            o0[0] = f2bf(v0.x); o0[1] = f2bf(v0.y); o0[2] = f2bf(v0.z); o0[3] = f2bf(v0.w);
            o0[4] = f2bf(v1.x); o0[5] = f2bf(v1.y); o0[6] = f2bf(v1.z); o0[7] = f2bf(v1.w);
            o1[0] = f2bf(v2.x); o1[1] = f2bf(v2.y); o1[2] = f2bf(v2.z); o1[3] = f2bf(v2.w);
            o1[4] = f2bf(v3.x); o1[5] = f2bf(v3.y); o1[6] = f2bf(v3.z); o1[7] = f2bf(v3.w);
            *(short8*)&As[ra * PST + ha * 16]     = o0;
            *(short8*)&As[ra * PST + ha * 16 + 8] = o1;

            // ---- B tile: 64 rows x 64 k, fp32 -> bf16
            const float4* pb = (const float4*)(W + (size_t)wrow * JD + k0 + ha * 16);
            float4 w0 = pb[0], w1 = pb[1], w2 = pb[2], w3 = pb[3];
            short8 p0, p1;
            p0[0] = f2bf(w0.x); p0[1] = f2bf(w0.y); p0[2] = f2bf(w0.z); p0[3] = f2bf(w0.w);
            p0[4] = f2bf(w1.x); p0[5] = f2bf(w1.y); p0[6] = f2bf(w1.z); p0[7] = f2bf(w1.w);
            p1[0] = f2bf(w2.x); p1[1] = f2bf(w2.y); p1[2] = f2bf(w2.z); p1[3] = f2bf(w2.w);
            p1[4] = f2bf(w3.x); p1[5] = f2bf(w3.y); p1[6] = f2bf(w3.z); p1[7] = f2bf(w3.w);
            *(short8*)&Bs[ra * PST + ha * 16]     = p0;
            *(short8*)&Bs[ra * PST + ha * 16 + 8] = p1;
        }
        __syncthreads();
        #pragma unroll
        for (int h2 = 0; h2 < 2; h2++) {
            short8 af[2], bf[2];
            #pragma unroll
            for (int im = 0; im < 2; im++)
                af[im] = *(const short8*)&As[(wm * 32 + im * 16 + l16) * PST + h2 * 32 + q4 * 8];
            #pragma unroll
            for (int in = 0; in < 2; in++)
                bf[in] = *(const short8*)&Bs[(wn * 32 + in * 16 + l16) * PST + h2 * 32 + q4 * 8];
            #pragma unroll
            for (int im = 0; im < 2; im++)
                #pragma unroll
                for (int in = 0; in < 2; in++)
                    acc[im][in] = __builtin_amdgcn_mfma_f32_16x16x32_bf16(
                        af[im], bf[in], acc[im][in], 0, 0, 0);
        }
    }
    #pragma unroll
    for (int im = 0; im < 2; im++) {
        int mb = bx * 64 + wm * 32 + im * 16 + q4 * 4;
        #pragma unroll
        for (int rr = 0; rr < 4; rr++) {
            int m = mb + rr;
            if (m < M) {
                #pragma unroll
                for (int in = 0; in < 2; in++) {
                    int j = by * 64 + wn * 32 + in * 16 + l16;
                    C[(size_t)m * JD + j] = acc[im][in][rr] + bias[j];
                }
            }
        }
    }
}

// ---------------------------------------------------------------------------
// Kernel 3: FUSED act + vocab GEMM.
// v3: B-fragments now read from fragment-native WbF -> every B load is one
// contiguous 1 KiB wave read (was a 64-line 1024-B-strided gather that
// saturated the per-CU L1/TA port). Same math, same double-buffer structure.
// 64-row M-tile (LDS 66,560 B -> 2 blocks/CU), 4 waves (1x4), wave tile
// 64x128, acc 4x8 floatx4.
// ---------------------------------------------------------------------------
#define AST 520
__global__ __launch_bounds__(256, 2) void fused_joiner(
    const float* __restrict__ enc_p, const float* __restrict__ dec_p,
    const short* __restrict__ WbF, const float* __restrict__ b_out,
    float* __restrict__ out)
{
    __shared__ short As[64 * AST];   // 66,560 B -> 2 blocks/CU
    int tid = threadIdx.x;
    int bx = blockIdx.x;

    // ---- Phase 1: act tile (64 m-rows x 512 j) -> LDS
    {
        int rsub = tid >> 7;            // 0..1 rows per pass
        int jf = (tid & 127) * 4;       // fp32 j offset, coalesced per row
        #pragma unroll 4
        for (int pass = 0; pass < 32; pass++) {
            int row = pass * 2 + rsub;
            int m = bx * 64 + row;
            int er = m / 50;            // n*200 + t
            int n  = m / 10000;
            int dr = n * 50 + (m - er * 50);
            float4 e = *(const float4*)(enc_p + (size_t)er * JD + jf);
            float4 d = *(const float4*)(dec_p + (size_t)dr * JD + jf);
            short4v o;
            o[0] = f2bf(fast_tanh(e.x + d.x));
            o[1] = f2bf(fast_tanh(e.y + d.y));
            o[2] = f2bf(fast_tanh(e.z + d.z));
            o[3] = f2bf(fast_tanh(e.w + d.w));
            *(short4v*)&As[row * AST + jf] = o;
        }
    }
    __syncthreads();

    // ---- Phase 2: GEMM out[64 x 512] = act x Wb^T over K=512
    int lane = tid & 63, wn = tid >> 6;   // 4 waves, 1x4 grid
    int l16 = lane & 15, q4 = lane >> 4;

    floatx4 acc[4][8];
    #pragma unroll
    for (int a = 0; a < 4; a++)
        #pragma unroll
        for (int b = 0; b < 8; b++) acc[a][b] = (floatx4){0.f, 0.f, 0.f, 0.f};

    int abase[4];
    #pragma unroll
    for (int im = 0; im < 4; im++)
        abase[im] = (im * 16 + l16) * AST + q4 * 8;
    // Fragment-native WbF offsets: vblk = wn*8+in; lane term q4*128 + l16*8.
    // Per (in, ks) the wave reads WbF[boff[in] + ks*512 .. +1KiB) contiguously.
    int boff[8];
    #pragma unroll
    for (int in = 0; in < 8; in++)
        boff[in] = (wn * 8 + in) * 8192 + q4 * 128 + l16 * 8;

    // B double-buffer from L2-resident WbF (512 KB)
    short8 b0[8], b1[8];
    #pragma unroll
    for (int in = 0; in < 8; in++)
        b0[in] = *(const short8*)(WbF + boff[in]);          // ks = 0

    for (int ks = 0; ks < 16; ks += 2) {
        #pragma unroll
        for (int in = 0; in < 8; in++)
            b1[in] = *(const short8*)(WbF + boff[in] + (ks + 1) * 512);
        {
            int k0 = ks * 32;
            short8 af[4];
            #pragma unroll
            for (int im = 0; im < 4; im++)
                af[im] = *(const short8*)&As[abase[im] + k0];
            #pragma unroll
            for (int im = 0; im < 4; im++)
                #pragma unroll
                for (int in = 0; in < 8; in++)
                    acc[im][in] = __builtin_amdgcn_mfma_f32_16x16x32_bf16(
                        af[im], b0[in], acc[im][in], 0, 0, 0);
        }
        if (ks + 2 < 16) {
            #pragma unroll
            for (int in = 0; in < 8; in++)
                b0[in] = *(const short8*)(WbF + boff[in] + (ks + 2) * 512);
        }
        {
            int k1 = (ks + 1) * 32;
            short8 af[4];
            #pragma unroll
            for (int im = 0; im < 4; im++)
                af[im] = *(const short8*)&As[abase[im] + k1];
            #pragma unroll
            for (int im = 0; im < 4; im++)
                #pragma unroll
                for (int in = 0; in < 8; in++)
                    acc[im][in] = __builtin_amdgcn_mfma_f32_16x16x32_bf16(
                        af[im], b1[in], acc[im][in], 0, 0, 0);
        }
    }

    // ---- Epilogue: bias + store (m always < 80000; guard v < 500)
    float bo[8];
    #pragma unroll
    for (int in = 0; in < 8; in++) {
        int v = wn * 128 + in * 16 + l16;
        bo[in] = (v < VV) ? b_out[v] : 0.f;
    }
    #pragma unroll
    for (int im = 0; im < 4; im++) {
        int mb = bx * 64 + im * 16 + q4 * 4;
        #pragma unroll
        for (int rr = 0; rr < 4; rr++) {
            size_t orow = (size_t)(mb + rr) * VV;
            #pragma unroll
            for (int in = 0; in < 8; in++) {
                int v = wn * 128 + in * 16 + l16;
                if (v < VV) out[orow + v] = acc[im][in][rr] + bo[in];
            }
        }
    }
}

// ---------------------------------------------------------------------------
extern "C" void kernel_launch(void* const* d_in, const int* in_sizes, int n_in,
                              void* d_out, int out_size, void* d_ws, size_t ws_size,
                              hipStream_t stream)
{
    const float* enc   = (const float*)d_in[0];
    const float* dec   = (const float*)d_in[1];
    const float* Wenc  = (const float*)d_in[2];
    const float* b_enc = (const float*)d_in[3];
    const float* Wdec  = (const float*)d_in[4];
    const float* b_dec = (const float*)d_in[5];
    const float* Wout  = (const float*)d_in[6];
    const float* b_out = (const float*)d_in[7];
    float* out = (float*)d_out;

    // ws layout (bytes): ~4.6 MB total
    char* ws = (char*)d_ws;
    short* WbF   = (short*)(ws + 0);          // 512*512 bf16 = 524,288 B
    float* enc_p = (float*)(ws + 524288);     // 1600*512 f32 = 3,276,800 B
    float* dec_p = (float*)(ws + 3801088);    //  400*512 f32 =   819,200 B

    prep_kernel<<<128, 256, 0, stream>>>(Wout, WbF);
    proj_gemm<<<dim3(32, 8), 256, 0, stream>>>(enc, dec, Wenc, Wdec,
                                               b_enc, b_dec, enc_p, dec_p);
    fused_joiner<<<1250, 256, 0, stream>>>(enc_p, dec_p, WbF, b_out, out);
}